// Round 1
// baseline (1121.843 us; speedup 1.0000x reference)
//
#include <hip/hip_runtime.h>

using u16 = unsigned short;
using u32 = unsigned int;
using u64 = unsigned long long;

#define NPTS   16384
#define NPER   8192
#define KNN    16
#define NKROWS (NPTS*KNN)
#define HD     128

typedef _Float16 half8 __attribute__((ext_vector_type(8)));
typedef float    floatx4 __attribute__((ext_vector_type(4)));

__device__ __forceinline__ u16  f2h(float f){ _Float16 h=(_Float16)f; return __builtin_bit_cast(u16,h); }
__device__ __forceinline__ float h2f(u16 u){ return (float)__builtin_bit_cast(_Float16,u); }
__device__ __forceinline__ u32 umin32(u32 a,u32 b){ return a<b?a:b; }
__device__ __forceinline__ u32 umax32(u32 a,u32 b){ return a>b?a:b; }

// ---------------------------------------------------------------- prep
__global__ __launch_bounds__(256) void pack_coords(const int* __restrict__ coords, u32* __restrict__ pc){
    int i = blockIdx.x*256 + threadIdx.x;            // 16384 points
    pc[i] = (u32)coords[3*i] | ((u32)coords[3*i+1]<<8) | ((u32)coords[3*i+2]<<16);
}

struct WPtrs { const float* p[8]; };
// wt[(t*2+l)*16384 + n*128 + k] = f16( W_t[l][k][n] )   (transposed: row n = out col, k contiguous)
__global__ __launch_bounds__(256) void prep_weights(WPtrs wp, u16* __restrict__ wt){
    int idx = blockIdx.x*256 + threadIdx.x;          // 8*2*16384
    int t = idx>>15, rem = idx&32767;
    int l = rem>>14, e = rem&16383;
    int n = e>>7, k = e&127;
    wt[idx] = f2h(wp.p[t][l*16384 + k*128 + n]);
}

// ---------------------------------------------------------------- KNN
// block: 256 threads = 32 queries x 8 chunks of 1024 candidates. grid 512.
__global__ __launch_bounds__(256) void knn_kernel(const u32* __restrict__ pc, int* __restrict__ idx_g,
                                                  float* __restrict__ rel, u64* __restrict__ sM){
    __shared__ u32 sc[NPER];
    __shared__ u32 mg[32*8*16];
    __shared__ u64 red[9];
    int tid = threadIdx.x;
    int scene = blockIdx.x>>8;
    int qbase = (blockIdx.x&255)*32;
    for (int i=tid;i<NPER;i+=256) sc[i]=pc[scene*NPER+i];
    if (tid<9) red[tid]=0;
    __syncthreads();

    int q = tid&31, c = tid>>5;
    u32 myp = sc[qbase+q];
    int qx=myp&255, qy=(myp>>8)&255, qz=(myp>>16)&255;
    u32 keys[16];
#pragma unroll
    for (int j=0;j<16;j++) keys[j]=0xFFFFFFFFu;
    int base = c*1024;
    for (int i=0;i<1024;i++){
        u32 p = sc[base+i];
        int dx=(int)(p&255)-qx, dy=(int)((p>>8)&255)-qy, dz=(int)((p>>16)&255)-qz;
        u32 d2 = (u32)(dx*dx+dy*dy+dz*dz);
        u32 key = (d2<<13) | (u32)(base+i);          // lexicographic (d2, idx) -> matches lax.top_k ties
        if (key < keys[15]){
            u32 t = key;
#pragma unroll
            for (int j=0;j<16;j++){ u32 lo=umin32(keys[j],t); t=umax32(keys[j],t); keys[j]=lo; }
        }
    }
#pragma unroll
    for (int j=0;j<16;j++) mg[(q*8+c)*16+j]=keys[j];
    __syncthreads();

    if (tid<32){
        int n = scene*NPER + qbase + tid;
        u32 mp = sc[qbase+tid];
        int ax=mp&255, ay=(mp>>8)&255, az=(mp>>16)&255;
        int heads[8]={0,0,0,0,0,0,0,0};
        long long s0=0,s1=0,s2=0,m00=0,m11=0,m22=0,m01=0,m02=0,m12=0;
        for (int out=0;out<16;out++){
            u32 best=0xFFFFFFFFu; int bc=0;
#pragma unroll
            for (int c2=0;c2<8;c2++){
                u32 v = (heads[c2]<16)? mg[(tid*8+c2)*16+heads[c2]] : 0xFFFFFFFFu;
                if (v<best){ best=v; bc=c2; }
            }
#pragma unroll
            for (int c2=0;c2<8;c2++) if (bc==c2) heads[c2]++;
            int j = (int)(best & 8191u);
            idx_g[(size_t)n*KNN+out] = scene*NPER + j;
            u32 p = sc[j];
            int dx=(int)(p&255)-ax, dy=(int)((p>>8)&255)-ay, dz=(int)((p>>16)&255)-az;
            size_t ro = ((size_t)n*KNN+out)*3;
            rel[ro]=(float)dx; rel[ro+1]=(float)dy; rel[ro+2]=(float)dz;
            s0+=dx; s1+=dy; s2+=dz;
            m00+=dx*dx; m11+=dy*dy; m22+=dz*dz; m01+=dx*dy; m02+=dx*dz; m12+=dy*dz;
        }
        atomicAdd(&red[0],(u64)s0); atomicAdd(&red[1],(u64)s1); atomicAdd(&red[2],(u64)s2);
        atomicAdd(&red[3],(u64)m00); atomicAdd(&red[4],(u64)m11); atomicAdd(&red[5],(u64)m22);
        atomicAdd(&red[6],(u64)m01); atomicAdd(&red[7],(u64)m02); atomicAdd(&red[8],(u64)m12);
    }
    __syncthreads();
    if (tid==0){
#pragma unroll
        for (int j=0;j<9;j++) atomicAdd(&sM[j], red[j]);
    }
}

// analytic BN affine for the 3->H layer: stats of rel@W_d1 + b from int64 (s, M=rel^T rel)
__global__ __launch_bounds__(256) void finalize_d1(const u64* __restrict__ sM, const float* __restrict__ W_d1,
        const float* __restrict__ b_d1, const float* __restrict__ g, const float* __restrict__ beta,
        float* __restrict__ A, float* __restrict__ C){
    int tid=threadIdx.x; int l=tid>>7, c=tid&127;
    double s0=(double)(long long)sM[0], s1=(double)(long long)sM[1], s2=(double)(long long)sM[2];
    double m00=(double)(long long)sM[3], m11=(double)(long long)sM[4], m22=(double)(long long)sM[5];
    double m01=(double)(long long)sM[6], m02=(double)(long long)sM[7], m12=(double)(long long)sM[8];
    double w0=W_d1[l*384+c], w1=W_d1[l*384+128+c], w2=W_d1[l*384+256+c];
    double b =b_d1[l*128+c];
    double S = s0*w0+s1*w1+s2*w2;
    double Q = m00*w0*w0+m11*w1*w1+m22*w2*w2 + 2.0*(m01*w0*w1+m02*w0*w2+m12*w1*w2);
    double cnt = (double)NKROWS;
    double mean = S/cnt + b;
    double ex2  = (Q + 2.0*b*S)/cnt + b*b;
    double var  = ex2 - mean*mean;
    float a = g[l*128+c] * (float)(1.0/sqrt(var+1e-5));
    A[l*128+c]=a; C[l*128+c]=beta[l*128+c]-(float)mean*a;
}

// ---------------------------------------------------------------- column stats + BN finalize
template<int IS16>
__global__ __launch_bounds__(256) void colstats(const void* __restrict__ xp, int rows, double* __restrict__ sums){
    int c=threadIdx.x&127, sub=threadIdx.x>>7;
    float s=0.f, s2=0.f;
    for (int r=blockIdx.x*2+sub; r<rows; r+=gridDim.x*2){
        float v = IS16 ? h2f(((const u16*)xp)[(size_t)r*HD+c]) : ((const float*)xp)[(size_t)r*HD+c];
        s+=v; s2+=v*v;
    }
    __shared__ float rs[2][HD], rq[2][HD];
    rs[sub][c]=s; rq[sub][c]=s2;
    __syncthreads();
    if (sub==0){
        s+=rs[1][c]; s2+=rq[1][c];
        unsafeAtomicAdd(&sums[c],   (double)s);
        unsafeAtomicAdd(&sums[HD+c],(double)s2);
    }
}

__global__ void finalize_affine(double* __restrict__ sums, const float* __restrict__ g,
        const float* __restrict__ b, double cnt, float* __restrict__ A, float* __restrict__ C){
    int c=threadIdx.x;
    double mean=sums[c]/cnt, ex2=sums[HD+c]/cnt;
    double var=ex2-mean*mean;
    float a = g[c] * (float)(1.0/sqrt(var+1e-5));
    A[c]=a; C[c]=b[c]-(float)mean*a;
    sums[c]=0.0; sums[HD+c]=0.0;                     // reset for next stage
}

// ---------------------------------------------------------------- GEMM (128x128 tile, K=128, MFMA f16)
struct CompF32 {      // A row = src row (fp32 -> f16)
    const float* src;
    __device__ __forceinline__ void stage(u16* As,int R0,int k0,int tid) const {
#pragma unroll
        for (int u=0;u<8;u++){
            int flat=u*256+tid, row=flat>>4, c4=flat&15; int k=k0+c4*4;
            const float4 v=*(const float4*)(src+(size_t)(R0+row)*HD+k);
            ushort4 o; o.x=f2h(v.x); o.y=f2h(v.y); o.z=f2h(v.z); o.w=f2h(v.w);
            *(ushort4*)(As+row*72+c4*4)=o;
        }
    }
};
struct CompF32Aff {   // A row = BN-affine(src row)
    const float* src; const float* Aa; const float* Ca;
    __device__ __forceinline__ void stage(u16* As,int R0,int k0,int tid) const {
#pragma unroll
        for (int u=0;u<8;u++){
            int flat=u*256+tid, row=flat>>4, c4=flat&15; int k=k0+c4*4;
            const float4 v=*(const float4*)(src+(size_t)(R0+row)*HD+k);
            ushort4 o;
            o.x=f2h(v.x*Aa[k]+Ca[k]);     o.y=f2h(v.y*Aa[k+1]+Ca[k+1]);
            o.z=f2h(v.z*Aa[k+2]+Ca[k+2]); o.w=f2h(v.w*Aa[k+3]+Ca[k+3]);
            *(ushort4*)(As+row*72+c4*4)=o;
        }
    }
};
struct CompPose1 {    // A row = relu(affine(rel @ W_d1 + b_d1))   (3->128 on the fly)
    const float* rel; const float* Wd1; const float* bd1; const float* Aa; const float* Ca;
    __device__ __forceinline__ void stage(u16* As,int R0,int k0,int tid) const {
#pragma unroll
        for (int u=0;u<8;u++){
            int flat=u*256+tid, row=flat>>4, c4=flat&15; int k=k0+c4*4; int R=R0+row;
            float r0=rel[(size_t)R*3], r1=rel[(size_t)R*3+1], r2=rel[(size_t)R*3+2];
            ushort4 o;
#pragma unroll
            for (int j=0;j<4;j++){
                int kk=k+j;
                float x = r0*Wd1[kk] + r1*Wd1[HD+kk] + r2*Wd1[2*HD+kk] + bd1[kk];
                x = fmaxf(x*Aa[kk]+Ca[kk], 0.f);
                ((u16*)&o)[j]=f2h(x);
            }
            *(ushort4*)(As+row*72+c4*4)=o;
        }
    }
};
struct CompA0 {       // A row = q[n] - kpsi[gidx] + affine(pose2)
    const float* q; const float* kp; const u16* pose; const int* gidx; const float* Aa; const float* Ca;
    __device__ __forceinline__ void stage(u16* As,int R0,int k0,int tid) const {
#pragma unroll
        for (int u=0;u<8;u++){
            int flat=u*256+tid, row=flat>>4, c4=flat&15; int k=k0+c4*4; int R=R0+row;
            int n=R>>4; int g=gidx[R];
            const float4 qv=*(const float4*)(q +(size_t)n*HD+k);
            const float4 kv=*(const float4*)(kp+(size_t)g*HD+k);
            const ushort4 pv=*(const ushort4*)(pose+(size_t)R*HD+k);
            ushort4 o;
            o.x=f2h(qv.x-kv.x + h2f(pv.x)*Aa[k]  +Ca[k]);
            o.y=f2h(qv.y-kv.y + h2f(pv.y)*Aa[k+1]+Ca[k+1]);
            o.z=f2h(qv.z-kv.z + h2f(pv.z)*Aa[k+2]+Ca[k+2]);
            o.w=f2h(qv.w-kv.w + h2f(pv.w)*Aa[k+3]+Ca[k+3]);
            *(ushort4*)(As+row*72+c4*4)=o;
        }
    }
};
struct CompH16AffRelu { // A row = relu(affine(f16 src))
    const u16* src; const float* Aa; const float* Ca;
    __device__ __forceinline__ void stage(u16* As,int R0,int k0,int tid) const {
#pragma unroll
        for (int u=0;u<8;u++){
            int flat=u*256+tid, row=flat>>4, c4=flat&15; int k=k0+c4*4;
            const ushort4 v=*(const ushort4*)(src+(size_t)(R0+row)*HD+k);
            ushort4 o;
            o.x=f2h(fmaxf(h2f(v.x)*Aa[k]  +Ca[k],  0.f));
            o.y=f2h(fmaxf(h2f(v.y)*Aa[k+1]+Ca[k+1],0.f));
            o.z=f2h(fmaxf(h2f(v.z)*Aa[k+2]+Ca[k+2],0.f));
            o.w=f2h(fmaxf(h2f(v.w)*Aa[k+3]+Ca[k+3],0.f));
            *(ushort4*)(As+row*72+c4*4)=o;
        }
    }
};

template<class Comp, bool OUT16, bool HASBIAS>
__global__ __launch_bounds__(256) void gemm128(Comp comp, const u16* __restrict__ Wt,
        const float* __restrict__ bias, void* __restrict__ outp){
    __shared__ __align__(16) u16 As[128*72];   // row stride 72 (=144B = 9x16B): conflict-free b128 reads
    __shared__ __align__(16) u16 Bs[128*72];   // Bs[n][k] = W[k][n]
    int tid=threadIdx.x;
    int R0=blockIdx.x*128;
    int lane=tid&63, wave=tid>>6, quad=lane>>4, r16=lane&15;
    int wm=wave>>1, wn=wave&1;
    floatx4 acc[4][4]={};
#pragma unroll
    for (int ks=0;ks<2;ks++){
        int k0=ks*64;
        comp.stage(As,R0,k0,tid);
#pragma unroll
        for (int u=0;u<4;u++){
            int flat=u*256+tid, n=flat>>3, c8=flat&7;
            *(int4*)(Bs+n*72+c8*8) = *(const int4*)(Wt+n*HD+k0+c8*8);
        }
        __syncthreads();
#pragma unroll
        for (int kk2=0;kk2<2;kk2++){
            half8 aF[4], bF[4];
#pragma unroll
            for (int mi=0;mi<4;mi++) aF[mi]=*(const half8*)(As+(wm*64+mi*16+r16)*72 + kk2*32+quad*8);
#pragma unroll
            for (int ni=0;ni<4;ni++) bF[ni]=*(const half8*)(Bs+(wn*64+ni*16+r16)*72 + kk2*32+quad*8);
#pragma unroll
            for (int mi=0;mi<4;mi++)
#pragma unroll
                for (int ni=0;ni<4;ni++)
                    acc[mi][ni]=__builtin_amdgcn_mfma_f32_16x16x32_f16(aF[mi],bF[ni],acc[mi][ni],0,0,0);
        }
        __syncthreads();
    }
#pragma unroll
    for (int mi=0;mi<4;mi++)
#pragma unroll
        for (int ni=0;ni<4;ni++){
            int col=wn*64+ni*16+r16;
            float bv = HASBIAS ? bias[col] : 0.f;
#pragma unroll
            for (int rg=0;rg<4;rg++){
                int row=R0+wm*64+mi*16+quad*4+rg;     // C/D: col=lane&15, row=quad*4+reg (m89)
                float v=acc[mi][ni][rg]+bv;
                if (OUT16) ((u16*)outp)[(size_t)row*HD+col]=f2h(v);
                else       ((float*)outp)[(size_t)row*HD+col]=v;
            }
        }
}

// ---------------------------------------------------------------- softmax-aggregate + residual
__global__ __launch_bounds__(256) void aggregate(const u16* __restrict__ a2, const u16* __restrict__ pose,
        const float* __restrict__ vv, const int* __restrict__ gidx,
        const float* __restrict__ Ag2, const float* __restrict__ Cg2,
        const float* __restrict__ Ad2, const float* __restrict__ Cd2, float* __restrict__ y){
    int c=threadIdx.x&127, h=threadIdx.x>>7;
    int n=blockIdx.x*2+h;
    float sA=Ag2[c], sC=Cg2[c], pA=Ad2[c], pC=Cd2[c];
    float av[16]; float m=-1e30f;
#pragma unroll
    for (int k=0;k<16;k++){ float a=h2f(a2[((size_t)n*16+k)*HD+c])*sA+sC; av[k]=a; m=fmaxf(m,a); }
    float sum=0.f;
#pragma unroll
    for (int k=0;k<16;k++){ float e=__expf(av[k]-m); av[k]=e; sum+=e; }
    float acc=0.f;
#pragma unroll
    for (int k=0;k<16;k++){
        int g=gidx[n*16+k];
        float pv = h2f(pose[((size_t)n*16+k)*HD+c])*pA+pC + vv[(size_t)g*HD+c];
        acc += av[k]*pv;
    }
    y[(size_t)n*HD+c]=acc/sum;
}

__global__ __launch_bounds__(256) void residual(const float* __restrict__ ydown, const float* __restrict__ A,
        const float* __restrict__ C, const float* __restrict__ fin, float* __restrict__ fout){
    size_t i=(size_t)blockIdx.x*256+threadIdx.x; int c=(int)(i&127);
    fout[i]=ydown[i]*A[c]+C[c]+fin[i];
}

// ---------------------------------------------------------------- launch
extern "C" void kernel_launch(void* const* d_in, const int* in_sizes, int n_in,
                              void* d_out, int out_size, void* d_ws, size_t ws_size,
                              hipStream_t stream){
    const int*   coords=(const int*)d_in[0];
    const float* feats=(const float*)d_in[1];
    const float* W_top=(const float*)d_in[2];
    const float* g_top=(const float*)d_in[3];
    const float* bt_top=(const float*)d_in[4];
    const float* W_phi=(const float*)d_in[5];
    const float* W_psi=(const float*)d_in[6];
    const float* W_alp=(const float*)d_in[7];
    const float* W_d1=(const float*)d_in[8];
    const float* b_d1=(const float*)d_in[9];
    const float* g_d1=(const float*)d_in[10];
    const float* bt_d1=(const float*)d_in[11];
    const float* W_d2=(const float*)d_in[12];
    const float* b_d2=(const float*)d_in[13];
    const float* g_d2=(const float*)d_in[14];
    const float* bt_d2=(const float*)d_in[15];
    const float* W_g1=(const float*)d_in[16];
    const float* b_g1=(const float*)d_in[17];
    const float* g_g1=(const float*)d_in[18];
    const float* bt_g1=(const float*)d_in[19];
    const float* W_g2=(const float*)d_in[20];
    const float* b_g2=(const float*)d_in[21];
    const float* g_g2=(const float*)d_in[22];
    const float* bt_g2=(const float*)d_in[23];
    const float* W_dn=(const float*)d_in[24];
    const float* g_dn=(const float*)d_in[25];
    const float* bt_dn=(const float*)d_in[26];

    char* ws=(char*)d_ws;
    size_t off=0;
    auto carve=[&](size_t bytes)->char*{ char* p=ws+off; off=(off+bytes+255)&~(size_t)255; return p; };
    u32*    pc    =(u32*)   carve((size_t)NPTS*4);
    int*    idxg  =(int*)   carve((size_t)NKROWS*4);
    float*  rel   =(float*) carve((size_t)NKROWS*3*4);
    float*  h_pre =(float*) carve((size_t)NPTS*HD*4);
    float*  qb    =(float*) carve((size_t)NPTS*HD*4);
    float*  kpb   =(float*) carve((size_t)NPTS*HD*4);
    float*  vvb   =(float*) carve((size_t)NPTS*HD*4);
    float*  yb    =(float*) carve((size_t)NPTS*HD*4);
    float*  ydown =(float*) carve((size_t)NPTS*HD*4);
    float*  fbuf  =(float*) carve((size_t)NPTS*HD*4);
    u16*    wt    =(u16*)   carve((size_t)8*2*16384*2);
    char*   stats =         carve(4096);               // sums(2048) + sM(96), memset to 0
    double* sums  =(double*)stats;
    u64*    sM    =(u64*)(stats+2048);
    float*  aff   =(float*) carve(8192);
    float *A_top=aff, *C_top=aff+128, *A_d2=aff+256, *C_d2=aff+384,
          *A_g1=aff+512, *C_g1=aff+640, *A_g2=aff+768, *C_g2=aff+896,
          *A_dn=aff+1024, *C_dn=aff+1152, *A_d1=aff+1280, *C_d1=aff+1536;
    u16*    pose2 =(u16*)   carve((size_t)NKROWS*HD*2);
    u16*    abuf  =(u16*)   carve((size_t)NKROWS*HD*2);
    if (ws_size < off) return; // workspace too small; fail loudly via validation

    hipMemsetAsync(stats, 0, 4096, stream);
    pack_coords<<<dim3(NPTS/256),dim3(256),0,stream>>>(coords, pc);
    WPtrs wp{{W_top,W_phi,W_psi,W_alp,W_d2,W_g1,W_g2,W_dn}};
    prep_weights<<<dim3(8*2*16384/256),dim3(256),0,stream>>>(wp, wt);
    knn_kernel<<<dim3(512),dim3(256),0,stream>>>(pc, idxg, rel, sM);
    finalize_d1<<<dim3(1),dim3(256),0,stream>>>(sM, W_d1, b_d1, g_d1, bt_d1, A_d1, C_d1);

    const float* fin=feats;
    for (int l=0;l<2;l++){
        const u16* wt_top=wt+(0*2+l)*16384; const u16* wt_phi=wt+(1*2+l)*16384;
        const u16* wt_psi=wt+(2*2+l)*16384; const u16* wt_alp=wt+(3*2+l)*16384;
        const u16* wt_d2 =wt+(4*2+l)*16384; const u16* wt_g1 =wt+(5*2+l)*16384;
        const u16* wt_g2 =wt+(6*2+l)*16384; const u16* wt_dn =wt+(7*2+l)*16384;

        // h_pre = f @ W_top  ; BN stats ; affine folded into consumers
        gemm128<CompF32,false,false><<<dim3(NPTS/128),dim3(256),0,stream>>>(CompF32{fin}, wt_top, nullptr, h_pre);
        colstats<0><<<dim3(128),dim3(256),0,stream>>>(h_pre, NPTS, sums);
        finalize_affine<<<dim3(1),dim3(128),0,stream>>>(sums, g_top+l*128, bt_top+l*128, (double)NPTS, A_top, C_top);

        // q / kpsi / vv = BN(h) @ {W_phi,W_psi,W_alpha}
        gemm128<CompF32Aff,false,false><<<dim3(NPTS/128),dim3(256),0,stream>>>(CompF32Aff{h_pre,A_top,C_top}, wt_phi, nullptr, qb);
        gemm128<CompF32Aff,false,false><<<dim3(NPTS/128),dim3(256),0,stream>>>(CompF32Aff{h_pre,A_top,C_top}, wt_psi, nullptr, kpb);
        gemm128<CompF32Aff,false,false><<<dim3(NPTS/128),dim3(256),0,stream>>>(CompF32Aff{h_pre,A_top,C_top}, wt_alp, nullptr, vvb);

        // pose2_pre = relu(BN1(rel@W_d1+b_d1)) @ W_d2 + b_d2
        gemm128<CompPose1,true,true><<<dim3(NKROWS/128),dim3(256),0,stream>>>(
            CompPose1{rel, W_d1+l*384, b_d1+l*128, A_d1+l*128, C_d1+l*128}, wt_d2, b_d2+l*128, pose2);
        colstats<1><<<dim3(1024),dim3(256),0,stream>>>(pose2, NKROWS, sums);
        finalize_affine<<<dim3(1),dim3(128),0,stream>>>(sums, g_d2+l*128, bt_d2+l*128, (double)NKROWS, A_d2, C_d2);

        // a1_pre = (q - kpsi[g] + pose) @ W_g1 + b_g1
        gemm128<CompA0,true,true><<<dim3(NKROWS/128),dim3(256),0,stream>>>(
            CompA0{qb,kpb,pose2,idxg,A_d2,C_d2}, wt_g1, b_g1+l*128, abuf);
        colstats<1><<<dim3(1024),dim3(256),0,stream>>>(abuf, NKROWS, sums);
        finalize_affine<<<dim3(1),dim3(128),0,stream>>>(sums, g_g1+l*128, bt_g1+l*128, (double)NKROWS, A_g1, C_g1);

        // a2_pre = relu(BN(a1_pre)) @ W_g2 + b_g2   (in-place over abuf; row-blocks read before written)
        gemm128<CompH16AffRelu,true,true><<<dim3(NKROWS/128),dim3(256),0,stream>>>(
            CompH16AffRelu{abuf,A_g1,C_g1}, wt_g2, b_g2+l*128, abuf);
        colstats<1><<<dim3(1024),dim3(256),0,stream>>>(abuf, NKROWS, sums);
        finalize_affine<<<dim3(1),dim3(128),0,stream>>>(sums, g_g2+l*128, bt_g2+l*128, (double)NKROWS, A_g2, C_g2);

        // softmax over K + aggregate
        aggregate<<<dim3(NPTS/2),dim3(256),0,stream>>>(abuf, pose2, vvb, idxg, A_g2, C_g2, A_d2, C_d2, yb);

        // y @ W_down ; BN ; residual
        gemm128<CompF32,false,false><<<dim3(NPTS/128),dim3(256),0,stream>>>(CompF32{yb}, wt_dn, nullptr, ydown);
        colstats<0><<<dim3(128),dim3(256),0,stream>>>(ydown, NPTS, sums);
        finalize_affine<<<dim3(1),dim3(128),0,stream>>>(sums, g_dn+l*128, bt_dn+l*128, (double)NPTS, A_dn, C_dn);
        residual<<<dim3(NPTS*HD/256),dim3(256),0,stream>>>(ydown, A_dn, C_dn, fin, (l==1)?(float*)d_out:fbuf);
        fin=fbuf;
    }
}

// Round 2
// 638.270 us; speedup vs baseline: 1.7576x; 1.7576x over previous
//
#include <hip/hip_runtime.h>

using u16 = unsigned short;
using u32 = unsigned int;
using u64 = unsigned long long;

#define NPTS   16384
#define NPER   8192
#define KNN    16
#define NKROWS (NPTS*KNN)
#define HD     128
#define CAP    160   // per-wave candidate buffer slots

typedef _Float16 half8 __attribute__((ext_vector_type(8)));
typedef float    floatx4 __attribute__((ext_vector_type(4)));

__device__ __forceinline__ u16  f2h(float f){ _Float16 h=(_Float16)f; return __builtin_bit_cast(u16,h); }
__device__ __forceinline__ float h2f(u16 u){ return (float)__builtin_bit_cast(_Float16,u); }
__device__ __forceinline__ u32 umin32(u32 a,u32 b){ return a<b?a:b; }

// ---------------------------------------------------------------- prep
__global__ __launch_bounds__(256) void pack_coords(const int* __restrict__ coords, u32* __restrict__ pc){
    int i = blockIdx.x*256 + threadIdx.x;
    pc[i] = (u32)coords[3*i] | ((u32)coords[3*i+1]<<8) | ((u32)coords[3*i+2]<<16);
}

struct WPtrs { const float* p[8]; };
// wt[(t*2+l)*16384 + n*128 + k] = f16( W_t[l][k][n] )
__global__ __launch_bounds__(256) void prep_weights(WPtrs wp, u16* __restrict__ wt){
    int idx = blockIdx.x*256 + threadIdx.x;
    int t = idx>>15, rem = idx&32767;
    int l = rem>>14, e = rem&16383;
    int n = e>>7, k = e&127;
    wt[idx] = f2h(wp.p[t][l*16384 + k*128 + n]);
}

// ---------------------------------------------------------------- KNN v2: wave-per-query threshold-ballot scan
// grid 4096 x 256 threads; block = 4 waves = 4 queries; scene staged in LDS (32KB)
__global__ __launch_bounds__(256) void knn2(const u32* __restrict__ pc, int* __restrict__ idx_g,
                                            float* __restrict__ rel, u64* __restrict__ sM){
    __shared__ u32 sc[NPER];
    __shared__ u32 buf[4][CAP];
    __shared__ u64 red[9];
    int tid = threadIdx.x;
    int wave = tid>>6, lane = tid&63;
    int scene = blockIdx.x >> 11;                 // 2048 blocks per scene
    int q = (blockIdx.x & 2047)*4 + wave;         // query index within scene

    const uint4* s4 = (const uint4*)(pc + scene*NPER);
#pragma unroll
    for (int i=0;i<8;i++) ((uint4*)sc)[tid + i*256] = s4[tid + i*256];
    if (tid<9) red[tid]=0;
    if (lane<16) buf[wave][lane]=0xFFFFFFFFu;
    __syncthreads();

    u32 qp = sc[q];
    int qx=(int)(qp&255), qy=(int)((qp>>8)&255), qz=(int)((qp>>16)&255);
    u32 thresh = 0xFFFFFFFFu;
    u32 cnt = 16;                                  // buf[0..15] = current top-16 (sorted)

    auto merge = [&](){
        // wave-wide extract 16 smallest of buf[0..cnt) (cnt<=160), write back sorted
        u32 v0 = (lane      < (int)cnt) ? buf[wave][lane]      : 0xFFFFFFFFu;
        u32 v1 = (lane+64   < (int)cnt) ? buf[wave][lane+64]   : 0xFFFFFFFFu;
        u32 v2 = (lane+128  < (int)cnt) ? buf[wave][lane+128]  : 0xFFFFFFFFu;
        u32 out = 0;
#pragma unroll
        for (int r=0;r<16;r++){
            u32 m = umin32(umin32(v0,v1),v2);
#pragma unroll
            for (int o=32;o>=1;o>>=1) m = umin32(m, (u32)__shfl_xor((int)m, o, 64));
            if      (v0==m) v0=0xFFFFFFFFu;
            else if (v1==m) v1=0xFFFFFFFFu;
            else if (v2==m) v2=0xFFFFFFFFu;
            if (lane==r) out = m;
            thresh = m;                            // after loop: 16th smallest (uniform)
        }
        if (lane<16) buf[wave][lane] = out;
        cnt = 16;
    };

    for (int t=0;t<128;t++){
        u32 p = sc[t*64+lane];
        int dx=(int)(p&255)-qx, dy=(int)((p>>8)&255)-qy, dz=(int)((p>>16)&255)-qz;
        u32 d2 = (u32)(__mul24(dx,dx)+__mul24(dy,dy)+__mul24(dz,dz));
        u32 key = (d2<<13) | (u32)(t*64+lane);     // (d2, idx) lexicographic, matches lax.top_k ties
        u64 mask = __ballot(key < thresh);
        if (mask){
            u32 lt = __builtin_amdgcn_mbcnt_hi((u32)(mask>>32), __builtin_amdgcn_mbcnt_lo((u32)mask,0));
            if (key < thresh) buf[wave][cnt + lt] = key;
            cnt += (u32)__popcll(mask);
            if (cnt > CAP-64) merge();
        }
    }
    merge();                                        // final: buf[0..15] sorted ascending

    // epilogue: emit idx/rel + moment sums (for analytic d1-BN)
    int n = scene*NPER + q;
    u32 key = buf[wave][lane & 15];
    int dx=0,dy=0,dz=0;
    if (lane<16){
        int j = (int)(key & 8191u);
        idx_g[(size_t)n*KNN + lane] = scene*NPER + j;
        u32 p = sc[j];
        dx=(int)(p&255)-qx; dy=(int)((p>>8)&255)-qy; dz=(int)((p>>16)&255)-qz;
        size_t ro = ((size_t)n*KNN+lane)*3;
        rel[ro]=(float)dx; rel[ro+1]=(float)dy; rel[ro+2]=(float)dz;
    }
    int arr[9] = {dx,dy,dz, dx*dx,dy*dy,dz*dz, dx*dy,dx*dz,dy*dz};
#pragma unroll
    for (int o=32;o>=1;o>>=1)
#pragma unroll
        for (int j=0;j<9;j++) arr[j] += __shfl_xor(arr[j], o, 64);
    if (lane==0)
#pragma unroll
        for (int j=0;j<9;j++) atomicAdd(&red[j], (u64)(long long)arr[j]);
    __syncthreads();
    if (tid<9) atomicAdd(&sM[tid], red[tid]);
}

// analytic BN affine for the 3->H layer
__global__ __launch_bounds__(256) void finalize_d1(const u64* __restrict__ sM, const float* __restrict__ W_d1,
        const float* __restrict__ b_d1, const float* __restrict__ g, const float* __restrict__ beta,
        float* __restrict__ A, float* __restrict__ C){
    int tid=threadIdx.x; int l=tid>>7, c=tid&127;
    double s0=(double)(long long)sM[0], s1=(double)(long long)sM[1], s2=(double)(long long)sM[2];
    double m00=(double)(long long)sM[3], m11=(double)(long long)sM[4], m22=(double)(long long)sM[5];
    double m01=(double)(long long)sM[6], m02=(double)(long long)sM[7], m12=(double)(long long)sM[8];
    double w0=W_d1[l*384+c], w1=W_d1[l*384+128+c], w2=W_d1[l*384+256+c];
    double b =b_d1[l*128+c];
    double S = s0*w0+s1*w1+s2*w2;
    double Q = m00*w0*w0+m11*w1*w1+m22*w2*w2 + 2.0*(m01*w0*w1+m02*w0*w2+m12*w1*w2);
    double cnt = (double)NKROWS;
    double mean = S/cnt + b;
    double ex2  = (Q + 2.0*b*S)/cnt + b*b;
    double var  = ex2 - mean*mean;
    float a = g[l*128+c] * (float)(1.0/sqrt(var+1e-5));
    A[l*128+c]=a; C[l*128+c]=beta[l*128+c]-(float)mean*a;
}

// finalize BN affine from 64-slot fp64 partials (written by gemm epilogues); zeroes slots for next stage
__global__ void finalize_affine(double* __restrict__ P, const float* __restrict__ g,
        const float* __restrict__ b, double cnt, float* __restrict__ A, float* __restrict__ C){
    int c=threadIdx.x;
    double s=0.0, q=0.0;
    for (int k=0;k<64;k++){
        s+=P[k*256+c]; q+=P[k*256+128+c];
        P[k*256+c]=0.0; P[k*256+128+c]=0.0;
    }
    double mean=s/cnt, var=q/cnt-mean*mean;
    float a = g[c] * (float)(1.0/sqrt(var+1e-5));
    A[c]=a; C[c]=b[c]-(float)mean*a;
}

// ---------------------------------------------------------------- GEMM composers
struct CompF32 {      // A row = f32 src row
    const float* src;
    __device__ __forceinline__ void stage(u16* As,int R0,int k0,int tid) const {
#pragma unroll
        for (int u=0;u<8;u++){
            int flat=u*256+tid, row=flat>>4, c4=flat&15; int k=k0+c4*4;
            const float4 v=*(const float4*)(src+(size_t)(R0+row)*HD+k);
            ushort4 o; o.x=f2h(v.x); o.y=f2h(v.y); o.z=f2h(v.z); o.w=f2h(v.w);
            *(ushort4*)(As+row*72+c4*4)=o;
        }
    }
};
struct CompH16Aff {   // A row = affine(f16 src)
    const u16* src; const float* Aa; const float* Ca;
    __device__ __forceinline__ void stage(u16* As,int R0,int k0,int tid) const {
#pragma unroll
        for (int u=0;u<8;u++){
            int flat=u*256+tid, row=flat>>4, c4=flat&15; int k=k0+c4*4;
            const ushort4 v=*(const ushort4*)(src+(size_t)(R0+row)*HD+k);
            ushort4 o;
            o.x=f2h(h2f(v.x)*Aa[k]  +Ca[k]);   o.y=f2h(h2f(v.y)*Aa[k+1]+Ca[k+1]);
            o.z=f2h(h2f(v.z)*Aa[k+2]+Ca[k+2]); o.w=f2h(h2f(v.w)*Aa[k+3]+Ca[k+3]);
            *(ushort4*)(As+row*72+c4*4)=o;
        }
    }
};
struct CompH16AffRelu { // A row = relu(affine(f16 src))
    const u16* src; const float* Aa; const float* Ca;
    __device__ __forceinline__ void stage(u16* As,int R0,int k0,int tid) const {
#pragma unroll
        for (int u=0;u<8;u++){
            int flat=u*256+tid, row=flat>>4, c4=flat&15; int k=k0+c4*4;
            const ushort4 v=*(const ushort4*)(src+(size_t)(R0+row)*HD+k);
            ushort4 o;
            o.x=f2h(fmaxf(h2f(v.x)*Aa[k]  +Ca[k],  0.f));
            o.y=f2h(fmaxf(h2f(v.y)*Aa[k+1]+Ca[k+1],0.f));
            o.z=f2h(fmaxf(h2f(v.z)*Aa[k+2]+Ca[k+2],0.f));
            o.w=f2h(fmaxf(h2f(v.w)*Aa[k+3]+Ca[k+3],0.f));
            *(ushort4*)(As+row*72+c4*4)=o;
        }
    }
};
struct CompPose1 {    // A row = relu(affine(rel @ W_d1 + b_d1))
    const float* rel; const float* Wd1; const float* bd1; const float* Aa; const float* Ca;
    __device__ __forceinline__ void stage(u16* As,int R0,int k0,int tid) const {
#pragma unroll
        for (int u=0;u<8;u++){
            int flat=u*256+tid, row=flat>>4, c4=flat&15; int k=k0+c4*4; int R=R0+row;
            float r0=rel[(size_t)R*3], r1=rel[(size_t)R*3+1], r2=rel[(size_t)R*3+2];
            ushort4 o;
#pragma unroll
            for (int j=0;j<4;j++){
                int kk=k+j;
                float x = r0*Wd1[kk] + r1*Wd1[HD+kk] + r2*Wd1[2*HD+kk] + bd1[kk];
                x = fmaxf(x*Aa[kk]+Ca[kk], 0.f);
                ((u16*)&o)[j]=f2h(x);
            }
            *(ushort4*)(As+row*72+c4*4)=o;
        }
    }
};
struct CompA0 {       // A row = q[n] - kpsi[gidx] + affine(pose2)   (all f16 inputs)
    const u16* q; const u16* kp; const u16* pose; const int* gidx; const float* Aa; const float* Ca;
    __device__ __forceinline__ void stage(u16* As,int R0,int k0,int tid) const {
#pragma unroll
        for (int u=0;u<8;u++){
            int flat=u*256+tid, row=flat>>4, c4=flat&15; int k=k0+c4*4; int R=R0+row;
            int n=R>>4; int g=gidx[R];
            const ushort4 qv=*(const ushort4*)(q +(size_t)n*HD+k);
            const ushort4 kv=*(const ushort4*)(kp+(size_t)g*HD+k);
            const ushort4 pv=*(const ushort4*)(pose+(size_t)R*HD+k);
            ushort4 o;
            o.x=f2h(h2f(qv.x)-h2f(kv.x) + h2f(pv.x)*Aa[k]  +Ca[k]);
            o.y=f2h(h2f(qv.y)-h2f(kv.y) + h2f(pv.y)*Aa[k+1]+Ca[k+1]);
            o.z=f2h(h2f(qv.z)-h2f(kv.z) + h2f(pv.z)*Aa[k+2]+Ca[k+2]);
            o.w=f2h(h2f(qv.w)-h2f(kv.w) + h2f(pv.w)*Aa[k+3]+Ca[k+3]);
            *(ushort4*)(As+row*72+c4*4)=o;
        }
    }
};

// ---------------------------------------------------------------- GEMM 128x128, K=128, MFMA f16, optional fused col-stats
template<class Comp, bool OUT16, bool HASBIAS, bool STATS>
__global__ __launch_bounds__(256) void gemm128(Comp comp, const u16* __restrict__ Wt,
        const float* __restrict__ bias, void* __restrict__ outp, double* __restrict__ statsP){
    __shared__ __align__(16) u16 As[128*72];
    __shared__ __align__(16) u16 Bs[128*72];
    __shared__ float cs2[2][128], cq2[2][128];
    int tid=threadIdx.x;
    int R0=blockIdx.x*128;
    int lane=tid&63, wave=tid>>6, quad=lane>>4, r16=lane&15;
    int wm=wave>>1, wn=wave&1;
    floatx4 acc[4][4]={};
#pragma unroll
    for (int ks=0;ks<2;ks++){
        int k0=ks*64;
        comp.stage(As,R0,k0,tid);
#pragma unroll
        for (int u=0;u<4;u++){
            int flat=u*256+tid, n=flat>>3, c8=flat&7;
            *(int4*)(Bs+n*72+c8*8) = *(const int4*)(Wt+n*HD+k0+c8*8);
        }
        __syncthreads();
#pragma unroll
        for (int kk2=0;kk2<2;kk2++){
            half8 aF[4], bF[4];
#pragma unroll
            for (int mi=0;mi<4;mi++) aF[mi]=*(const half8*)(As+(wm*64+mi*16+r16)*72 + kk2*32+quad*8);
#pragma unroll
            for (int ni=0;ni<4;ni++) bF[ni]=*(const half8*)(Bs+(wn*64+ni*16+r16)*72 + kk2*32+quad*8);
#pragma unroll
            for (int mi=0;mi<4;mi++)
#pragma unroll
                for (int ni=0;ni<4;ni++)
                    acc[mi][ni]=__builtin_amdgcn_mfma_f32_16x16x32_f16(aF[mi],bF[ni],acc[mi][ni],0,0,0);
        }
        __syncthreads();
    }
    float sAcc[4]={0,0,0,0}, qAcc[4]={0,0,0,0};
#pragma unroll
    for (int mi=0;mi<4;mi++)
#pragma unroll
        for (int ni=0;ni<4;ni++){
            int col=wn*64+ni*16+r16;
            float bv = HASBIAS ? bias[col] : 0.f;
#pragma unroll
            for (int rg=0;rg<4;rg++){
                int row=R0+wm*64+mi*16+quad*4+rg;
                float v=acc[mi][ni][rg]+bv;
                if (STATS){ sAcc[ni]+=v; qAcc[ni]+=v*v; }
                if (OUT16) ((u16*)outp)[(size_t)row*HD+col]=f2h(v);
                else       ((float*)outp)[(size_t)row*HD+col]=v;
            }
        }
    if (STATS){
#pragma unroll
        for (int ni=0;ni<4;ni++){
            float s=sAcc[ni], q=qAcc[ni];
            s += __shfl_xor(s,16,64); s += __shfl_xor(s,32,64);
            q += __shfl_xor(q,16,64); q += __shfl_xor(q,32,64);
            if (quad==0){
                int col=wn*64+ni*16+r16;
                cs2[wm][col]=s; cq2[wm][col]=q;
            }
        }
        __syncthreads();
        if (tid<128){
            int slot = blockIdx.x & 63;
            unsafeAtomicAdd(&statsP[slot*256+tid],     (double)(cs2[0][tid]+cs2[1][tid]));
            unsafeAtomicAdd(&statsP[slot*256+128+tid], (double)(cq2[0][tid]+cq2[1][tid]));
        }
    }
}

// ---------------------------------------------------------------- softmax-aggregate + residual
__global__ __launch_bounds__(256) void aggregate(const u16* __restrict__ a2, const u16* __restrict__ pose,
        const u16* __restrict__ vv, const int* __restrict__ gidx,
        const float* __restrict__ Ag2, const float* __restrict__ Cg2,
        const float* __restrict__ Ad2, const float* __restrict__ Cd2, float* __restrict__ y){
    int c=threadIdx.x&127, h=threadIdx.x>>7;
    int n=blockIdx.x*2+h;
    float sA=Ag2[c], sC=Cg2[c], pA=Ad2[c], pC=Cd2[c];
    float av[16]; float m=-1e30f;
#pragma unroll
    for (int k=0;k<16;k++){ float a=h2f(a2[((size_t)n*16+k)*HD+c])*sA+sC; av[k]=a; m=fmaxf(m,a); }
    float sum=0.f;
#pragma unroll
    for (int k=0;k<16;k++){ float e=__expf(av[k]-m); av[k]=e; sum+=e; }
    float acc=0.f;
#pragma unroll
    for (int k=0;k<16;k++){
        int g=gidx[n*16+k];
        float pv = h2f(pose[((size_t)n*16+k)*HD+c])*pA+pC + h2f(vv[(size_t)g*HD+c]);
        acc += av[k]*pv;
    }
    y[(size_t)n*HD+c]=acc/sum;
}

__global__ __launch_bounds__(256) void residual(const float* __restrict__ ydown, const float* __restrict__ A,
        const float* __restrict__ C, const float* __restrict__ fin, float* __restrict__ fout){
    size_t i=(size_t)blockIdx.x*256+threadIdx.x; int c=(int)(i&127);
    fout[i]=ydown[i]*A[c]+C[c]+fin[i];
}

// ---------------------------------------------------------------- launch
extern "C" void kernel_launch(void* const* d_in, const int* in_sizes, int n_in,
                              void* d_out, int out_size, void* d_ws, size_t ws_size,
                              hipStream_t stream){
    const int*   coords=(const int*)d_in[0];
    const float* feats=(const float*)d_in[1];
    const float* W_top=(const float*)d_in[2];
    const float* g_top=(const float*)d_in[3];
    const float* bt_top=(const float*)d_in[4];
    const float* W_phi=(const float*)d_in[5];
    const float* W_psi=(const float*)d_in[6];
    const float* W_alp=(const float*)d_in[7];
    const float* W_d1=(const float*)d_in[8];
    const float* b_d1=(const float*)d_in[9];
    const float* g_d1=(const float*)d_in[10];
    const float* bt_d1=(const float*)d_in[11];
    const float* W_d2=(const float*)d_in[12];
    const float* b_d2=(const float*)d_in[13];
    const float* g_d2=(const float*)d_in[14];
    const float* bt_d2=(const float*)d_in[15];
    const float* W_g1=(const float*)d_in[16];
    const float* b_g1=(const float*)d_in[17];
    const float* g_g1=(const float*)d_in[18];
    const float* bt_g1=(const float*)d_in[19];
    const float* W_g2=(const float*)d_in[20];
    const float* b_g2=(const float*)d_in[21];
    const float* g_g2=(const float*)d_in[22];
    const float* bt_g2=(const float*)d_in[23];
    const float* W_dn=(const float*)d_in[24];
    const float* g_dn=(const float*)d_in[25];
    const float* bt_dn=(const float*)d_in[26];

    char* ws=(char*)d_ws;
    size_t off=0;
    auto carve=[&](size_t bytes)->char*{ char* p=ws+off; off=(off+bytes+255)&~(size_t)255; return p; };
    u32*    pc    =(u32*)   carve((size_t)NPTS*4);
    int*    idxg  =(int*)   carve((size_t)NKROWS*4);
    float*  rel   =(float*) carve((size_t)NKROWS*3*4);
    u16*    h16   =(u16*)   carve((size_t)NPTS*HD*2);
    u16*    qb    =(u16*)   carve((size_t)NPTS*HD*2);
    u16*    kpb   =(u16*)   carve((size_t)NPTS*HD*2);
    u16*    vvb   =(u16*)   carve((size_t)NPTS*HD*2);
    float*  yb    =(float*) carve((size_t)NPTS*HD*4);
    float*  ydown =(float*) carve((size_t)NPTS*HD*4);
    float*  fbuf  =(float*) carve((size_t)NPTS*HD*4);
    u16*    wt    =(u16*)   carve((size_t)8*2*16384*2);
    char*   stats =         carve(64*256*8 + 256);      // P(131072) + sM(72)
    double* P     =(double*)stats;
    u64*    sM    =(u64*)(stats + 64*256*8);
    float*  aff   =(float*) carve(8192);
    float *A_top=aff, *C_top=aff+128, *A_d2=aff+256, *C_d2=aff+384,
          *A_g1=aff+512, *C_g1=aff+640, *A_g2=aff+768, *C_g2=aff+896,
          *A_dn=aff+1024, *C_dn=aff+1152, *A_d1=aff+1280, *C_d1=aff+1536;
    u16*    pose2 =(u16*)   carve((size_t)NKROWS*HD*2);
    u16*    abuf  =(u16*)   carve((size_t)NKROWS*HD*2);
    if (ws_size < off) return;

    hipMemsetAsync(stats, 0, 64*256*8 + 256, stream);
    pack_coords<<<dim3(NPTS/256),dim3(256),0,stream>>>(coords, pc);
    WPtrs wp{{W_top,W_phi,W_psi,W_alp,W_d2,W_g1,W_g2,W_dn}};
    prep_weights<<<dim3(8*2*16384/256),dim3(256),0,stream>>>(wp, wt);
    knn2<<<dim3(4096),dim3(256),0,stream>>>(pc, idxg, rel, sM);
    finalize_d1<<<dim3(1),dim3(256),0,stream>>>(sM, W_d1, b_d1, g_d1, bt_d1, A_d1, C_d1);

    const float* fin=feats;
    for (int l=0;l<2;l++){
        const u16* wt_top=wt+(0*2+l)*16384; const u16* wt_phi=wt+(1*2+l)*16384;
        const u16* wt_psi=wt+(2*2+l)*16384; const u16* wt_alp=wt+(3*2+l)*16384;
        const u16* wt_d2 =wt+(4*2+l)*16384; const u16* wt_g1 =wt+(5*2+l)*16384;
        const u16* wt_g2 =wt+(6*2+l)*16384; const u16* wt_dn =wt+(7*2+l)*16384;

        // h16 = f @ W_top (f16 out, stats fused)
        gemm128<CompF32,true,false,true><<<dim3(NPTS/128),dim3(256),0,stream>>>(CompF32{fin}, wt_top, nullptr, h16, P);
        finalize_affine<<<dim3(1),dim3(128),0,stream>>>(P, g_top+l*128, bt_top+l*128, (double)NPTS, A_top, C_top);

        // q / kpsi / vv = BN(h) @ {W_phi,W_psi,W_alpha} (f16 out, no stats)
        gemm128<CompH16Aff,true,false,false><<<dim3(NPTS/128),dim3(256),0,stream>>>(CompH16Aff{h16,A_top,C_top}, wt_phi, nullptr, qb, nullptr);
        gemm128<CompH16Aff,true,false,false><<<dim3(NPTS/128),dim3(256),0,stream>>>(CompH16Aff{h16,A_top,C_top}, wt_psi, nullptr, kpb, nullptr);
        gemm128<CompH16Aff,true,false,false><<<dim3(NPTS/128),dim3(256),0,stream>>>(CompH16Aff{h16,A_top,C_top}, wt_alp, nullptr, vvb, nullptr);

        // pose2 = relu(BN1(rel@W_d1+b_d1)) @ W_d2 + b_d2 (stats fused)
        gemm128<CompPose1,true,true,true><<<dim3(NKROWS/128),dim3(256),0,stream>>>(
            CompPose1{rel, W_d1+l*384, b_d1+l*128, A_d1+l*128, C_d1+l*128}, wt_d2, b_d2+l*128, pose2, P);
        finalize_affine<<<dim3(1),dim3(128),0,stream>>>(P, g_d2+l*128, bt_d2+l*128, (double)NKROWS, A_d2, C_d2);

        // a1 = (q - kpsi[g] + BN(pose2)) @ W_g1 + b_g1 (stats fused)
        gemm128<CompA0,true,true,true><<<dim3(NKROWS/128),dim3(256),0,stream>>>(
            CompA0{qb,kpb,pose2,idxg,A_d2,C_d2}, wt_g1, b_g1+l*128, abuf, P);
        finalize_affine<<<dim3(1),dim3(128),0,stream>>>(P, g_g1+l*128, bt_g1+l*128, (double)NKROWS, A_g1, C_g1);

        // a2 = relu(BN(a1)) @ W_g2 + b_g2 (in-place, stats fused)
        gemm128<CompH16AffRelu,true,true,true><<<dim3(NKROWS/128),dim3(256),0,stream>>>(
            CompH16AffRelu{abuf,A_g1,C_g1}, wt_g2, b_g2+l*128, abuf, P);
        finalize_affine<<<dim3(1),dim3(128),0,stream>>>(P, g_g2+l*128, bt_g2+l*128, (double)NKROWS, A_g2, C_g2);

        // softmax over K + aggregate
        aggregate<<<dim3(NPTS/2),dim3(256),0,stream>>>(abuf, pose2, vvb, idxg, A_g2, C_g2, A_d2, C_d2, yb);

        // y @ W_down (stats fused) ; BN ; residual
        gemm128<CompF32,false,false,true><<<dim3(NPTS/128),dim3(256),0,stream>>>(CompF32{yb}, wt_dn, nullptr, ydown, P);
        finalize_affine<<<dim3(1),dim3(128),0,stream>>>(P, g_dn+l*128, bt_dn+l*128, (double)NPTS, A_dn, C_dn);
        residual<<<dim3(NPTS*HD/256),dim3(256),0,stream>>>(ydown, A_dn, C_dn, fin, (l==1)?(float*)d_out:fbuf);
        fin=fbuf;
    }
}

// Round 3
// 559.477 us; speedup vs baseline: 2.0052x; 1.1408x over previous
//
#include <hip/hip_runtime.h>

using u16 = unsigned short;
using u32 = unsigned int;
using u64 = unsigned long long;

#define NPTS   16384
#define NPER   8192
#define KNN    16
#define NKROWS (NPTS*KNN)
#define HD     128
#define CAP    208   // per-wave candidate buffer slots (merge margin 128)
#define NSLOT  16    // fp64 stats partial slots

typedef _Float16 half8 __attribute__((ext_vector_type(8)));
typedef float    floatx4 __attribute__((ext_vector_type(4)));

__device__ __forceinline__ u16  f2h(float f){ _Float16 h=(_Float16)f; return __builtin_bit_cast(u16,h); }
__device__ __forceinline__ float h2f(u16 u){ return (float)__builtin_bit_cast(_Float16,u); }
__device__ __forceinline__ u32 umin32(u32 a,u32 b){ return a<b?a:b; }

// ---------------------------------------------------------------- prep
__global__ __launch_bounds__(256) void pack_coords(const int* __restrict__ coords, u32* __restrict__ pc){
    int i = blockIdx.x*256 + threadIdx.x;
    pc[i] = (u32)coords[3*i] | ((u32)coords[3*i+1]<<8) | ((u32)coords[3*i+2]<<16);
}

struct WPtrs { const float* p[8]; };
// wt[(t*2+l)*16384 + n*128 + k] = f16( W_t[l][k][n] )
__global__ __launch_bounds__(256) void prep_weights(WPtrs wp, u16* __restrict__ wt){
    int idx = blockIdx.x*256 + threadIdx.x;
    int t = idx>>15, rem = idx&32767;
    int l = rem>>14, e = rem&16383;
    int n = e>>7, k = e&127;
    wt[idx] = f2h(wp.p[t][l*16384 + k*128 + n]);
}

// ---------------------------------------------------------------- KNN v3: 8 waves/block, 2 cands/lane, prefetch
// grid 2048 x 512 threads; block = 8 waves = 8 queries; scene staged in LDS (32KB)
__global__ __launch_bounds__(512) void knn3(const u32* __restrict__ pc, int* __restrict__ idx_g,
                                            float* __restrict__ rel, u64* __restrict__ sM){
    __shared__ u32 sc[NPER];
    __shared__ u32 buf[8][CAP];
    __shared__ u64 red[9];
    int tid = threadIdx.x;
    int wave = tid>>6, lane = tid&63;
    int scene = blockIdx.x >> 10;                 // 1024 blocks per scene
    int q = (blockIdx.x & 1023)*8 + wave;

    const uint4* s4 = (const uint4*)(pc + scene*NPER);
#pragma unroll
    for (int i=0;i<4;i++) ((uint4*)sc)[tid + i*512] = s4[tid + i*512];
    if (tid<9) red[tid]=0;
    if (lane<16) buf[wave][lane]=0xFFFFFFFFu;
    __syncthreads();

    u32 qp = sc[q];
    int qx=(int)(qp&255), qy=(int)((qp>>8)&255), qz=(int)((qp>>16)&255);
    u32 thresh = 0xFFFFFFFFu;
    u32 cnt = 16;                                  // buf[0..15] = current top-16 (sorted)

    auto merge = [&](){
        u32 v0 = (lane      < (int)cnt) ? buf[wave][lane]      : 0xFFFFFFFFu;
        u32 v1 = (lane+64   < (int)cnt) ? buf[wave][lane+64]   : 0xFFFFFFFFu;
        u32 v2 = (lane+128  < (int)cnt) ? buf[wave][lane+128]  : 0xFFFFFFFFu;
        u32 v3 = (lane+192  < (int)cnt) ? buf[wave][lane+192]  : 0xFFFFFFFFu;
        u32 out = 0;
#pragma unroll
        for (int r=0;r<16;r++){
            u32 m = umin32(umin32(v0,v1),umin32(v2,v3));
#pragma unroll
            for (int o=32;o>=1;o>>=1) m = umin32(m, (u32)__shfl_xor((int)m, o, 64));
            if      (v0==m) v0=0xFFFFFFFFu;
            else if (v1==m) v1=0xFFFFFFFFu;
            else if (v2==m) v2=0xFFFFFFFFu;
            else if (v3==m) v3=0xFFFFFFFFu;
            if (lane==r) out = m;
            thresh = m;                            // after loop: 16th smallest (uniform)
        }
        if (lane<16) buf[wave][lane] = out;
        cnt = 16;
    };

    int lane2 = lane*2;
    uint2 p2 = ((const uint2*)sc)[lane];
    for (int t=0;t<64;t++){
        uint2 cur = p2;
        if (t<63) p2 = ((const uint2*)sc)[(t+1)*64+lane];
        int base = t*128 + lane2;
        u32 pa = cur.x;
        int dx0=(int)(pa&255)-qx, dy0=(int)((pa>>8)&255)-qy, dz0=(int)((pa>>16)&255)-qz;
        u32 d2_0 = (u32)(__mul24(dx0,dx0)+__mul24(dy0,dy0)+__mul24(dz0,dz0));
        u32 key0 = (d2_0<<13) + (u32)base;
        u32 pb = cur.y;
        int dx1=(int)(pb&255)-qx, dy1=(int)((pb>>8)&255)-qy, dz1=(int)((pb>>16)&255)-qz;
        u32 d2_1 = (u32)(__mul24(dx1,dx1)+__mul24(dy1,dy1)+__mul24(dz1,dz1));
        u32 key1 = (d2_1<<13) + (u32)(base+1);
        u64 m0 = __ballot(key0 < thresh);
        if (m0){
            u32 lt = __builtin_amdgcn_mbcnt_hi((u32)(m0>>32), __builtin_amdgcn_mbcnt_lo((u32)m0,0));
            if (key0 < thresh) buf[wave][cnt + lt] = key0;
            cnt += (u32)__popcll(m0);
        }
        u64 m1 = __ballot(key1 < thresh);
        if (m1){
            u32 lt = __builtin_amdgcn_mbcnt_hi((u32)(m1>>32), __builtin_amdgcn_mbcnt_lo((u32)m1,0));
            if (key1 < thresh) buf[wave][cnt + lt] = key1;
            cnt += (u32)__popcll(m1);
        }
        if (cnt > CAP-128) merge();
    }
    merge();

    // epilogue: emit idx/rel + moment sums (for analytic d1-BN)
    int n = scene*NPER + q;
    u32 key = buf[wave][lane & 15];
    int dx=0,dy=0,dz=0;
    if (lane<16){
        int j = (int)(key & 8191u);
        idx_g[(size_t)n*KNN + lane] = scene*NPER + j;
        u32 p = sc[j];
        dx=(int)(p&255)-qx; dy=(int)((p>>8)&255)-qy; dz=(int)((p>>16)&255)-qz;
        size_t ro = ((size_t)n*KNN+lane)*3;
        rel[ro]=(float)dx; rel[ro+1]=(float)dy; rel[ro+2]=(float)dz;
    }
    int arr[9] = {dx,dy,dz, dx*dx,dy*dy,dz*dz, dx*dy,dx*dz,dy*dz};
#pragma unroll
    for (int o=32;o>=1;o>>=1)
#pragma unroll
        for (int j=0;j<9;j++) arr[j] += __shfl_xor(arr[j], o, 64);
    if (lane==0)
#pragma unroll
        for (int j=0;j<9;j++) atomicAdd(&red[j], (u64)(long long)arr[j]);
    __syncthreads();
    if (tid<9) atomicAdd(&sM[tid], red[tid]);
}

// analytic BN affine for the 3->H layer
__global__ __launch_bounds__(256) void finalize_d1(const u64* __restrict__ sM, const float* __restrict__ W_d1,
        const float* __restrict__ b_d1, const float* __restrict__ g, const float* __restrict__ beta,
        float* __restrict__ A, float* __restrict__ C){
    int tid=threadIdx.x; int l=tid>>7, c=tid&127;
    double s0=(double)(long long)sM[0], s1=(double)(long long)sM[1], s2=(double)(long long)sM[2];
    double m00=(double)(long long)sM[3], m11=(double)(long long)sM[4], m22=(double)(long long)sM[5];
    double m01=(double)(long long)sM[6], m02=(double)(long long)sM[7], m12=(double)(long long)sM[8];
    double w0=W_d1[l*384+c], w1=W_d1[l*384+128+c], w2=W_d1[l*384+256+c];
    double b =b_d1[l*128+c];
    double S = s0*w0+s1*w1+s2*w2;
    double Q = m00*w0*w0+m11*w1*w1+m22*w2*w2 + 2.0*(m01*w0*w1+m02*w0*w2+m12*w1*w2);
    double cnt = (double)NKROWS;
    double mean = S/cnt + b;
    double ex2  = (Q + 2.0*b*S)/cnt + b*b;
    double var  = ex2 - mean*mean;
    float a = g[l*128+c] * (float)(1.0/sqrt(var+1e-5));
    A[l*128+c]=a; C[l*128+c]=beta[l*128+c]-(float)mean*a;
}

// finalize BN affine from NSLOT fp64 partials; zeroes slots for next stage
__global__ void finalize_affine(double* __restrict__ P, const float* __restrict__ g,
        const float* __restrict__ b, double cnt, float* __restrict__ A, float* __restrict__ C){
    int c=threadIdx.x;
    double s=0.0, q=0.0;
#pragma unroll
    for (int k=0;k<NSLOT;k++){
        s+=P[k*256+c]; q+=P[k*256+128+c];
        P[k*256+c]=0.0; P[k*256+128+c]=0.0;
    }
    double mean=s/cnt, var=q/cnt-mean*mean;
    float a = g[c] * (float)(1.0/sqrt(var+1e-5));
    A[c]=a; C[c]=b[c]-(float)mean*a;
}

// ---------------------------------------------------------------- GEMM composers
struct CompF32 {
    const float* src;
    __device__ __forceinline__ void stage(u16* As,int R0,int k0,int tid) const {
#pragma unroll
        for (int u=0;u<8;u++){
            int flat=u*256+tid, row=flat>>4, c4=flat&15; int k=k0+c4*4;
            const float4 v=*(const float4*)(src+(size_t)(R0+row)*HD+k);
            ushort4 o; o.x=f2h(v.x); o.y=f2h(v.y); o.z=f2h(v.z); o.w=f2h(v.w);
            *(ushort4*)(As+row*72+c4*4)=o;
        }
    }
};
struct CompH16Aff {
    const u16* src; const float* Aa; const float* Ca;
    __device__ __forceinline__ void stage(u16* As,int R0,int k0,int tid) const {
#pragma unroll
        for (int u=0;u<8;u++){
            int flat=u*256+tid, row=flat>>4, c4=flat&15; int k=k0+c4*4;
            const ushort4 v=*(const ushort4*)(src+(size_t)(R0+row)*HD+k);
            ushort4 o;
            o.x=f2h(h2f(v.x)*Aa[k]  +Ca[k]);   o.y=f2h(h2f(v.y)*Aa[k+1]+Ca[k+1]);
            o.z=f2h(h2f(v.z)*Aa[k+2]+Ca[k+2]); o.w=f2h(h2f(v.w)*Aa[k+3]+Ca[k+3]);
            *(ushort4*)(As+row*72+c4*4)=o;
        }
    }
};
struct CompH16AffRelu {
    const u16* src; const float* Aa; const float* Ca;
    __device__ __forceinline__ void stage(u16* As,int R0,int k0,int tid) const {
#pragma unroll
        for (int u=0;u<8;u++){
            int flat=u*256+tid, row=flat>>4, c4=flat&15; int k=k0+c4*4;
            const ushort4 v=*(const ushort4*)(src+(size_t)(R0+row)*HD+k);
            ushort4 o;
            o.x=f2h(fmaxf(h2f(v.x)*Aa[k]  +Ca[k],  0.f));
            o.y=f2h(fmaxf(h2f(v.y)*Aa[k+1]+Ca[k+1],0.f));
            o.z=f2h(fmaxf(h2f(v.z)*Aa[k+2]+Ca[k+2],0.f));
            o.w=f2h(fmaxf(h2f(v.w)*Aa[k+3]+Ca[k+3],0.f));
            *(ushort4*)(As+row*72+c4*4)=o;
        }
    }
};
struct CompPose1 {
    const float* rel; const float* Wd1; const float* bd1; const float* Aa; const float* Ca;
    __device__ __forceinline__ void stage(u16* As,int R0,int k0,int tid) const {
#pragma unroll
        for (int u=0;u<8;u++){
            int flat=u*256+tid, row=flat>>4, c4=flat&15; int k=k0+c4*4; int R=R0+row;
            float r0=rel[(size_t)R*3], r1=rel[(size_t)R*3+1], r2=rel[(size_t)R*3+2];
            ushort4 o;
#pragma unroll
            for (int j=0;j<4;j++){
                int kk=k+j;
                float x = r0*Wd1[kk] + r1*Wd1[HD+kk] + r2*Wd1[2*HD+kk] + bd1[kk];
                x = fmaxf(x*Aa[kk]+Ca[kk], 0.f);
                ((u16*)&o)[j]=f2h(x);
            }
            *(ushort4*)(As+row*72+c4*4)=o;
        }
    }
};
struct CompA0 {
    const u16* q; const u16* kp; const u16* pose; const int* gidx; const float* Aa; const float* Ca;
    __device__ __forceinline__ void stage(u16* As,int R0,int k0,int tid) const {
#pragma unroll
        for (int u=0;u<8;u++){
            int flat=u*256+tid, row=flat>>4, c4=flat&15; int k=k0+c4*4; int R=R0+row;
            int n=R>>4; int g=gidx[R];
            const ushort4 qv=*(const ushort4*)(q +(size_t)n*HD+k);
            const ushort4 kv=*(const ushort4*)(kp+(size_t)g*HD+k);
            const ushort4 pv=*(const ushort4*)(pose+(size_t)R*HD+k);
            ushort4 o;
            o.x=f2h(h2f(qv.x)-h2f(kv.x) + h2f(pv.x)*Aa[k]  +Ca[k]);
            o.y=f2h(h2f(qv.y)-h2f(kv.y) + h2f(pv.y)*Aa[k+1]+Ca[k+1]);
            o.z=f2h(h2f(qv.z)-h2f(kv.z) + h2f(pv.z)*Aa[k+2]+Ca[k+2]);
            o.w=f2h(h2f(qv.w)-h2f(kv.w) + h2f(pv.w)*Aa[k+3]+Ca[k+3]);
            *(ushort4*)(As+row*72+c4*4)=o;
        }
    }
};

// ---------------------------------------------------------------- GEMM 128x128, K=128, MFMA f16, fused col-stats
// grid.y selects weight/output (wtStride/outStride in elements) for multi-output launches
template<class Comp, bool OUT16, bool HASBIAS, bool STATS>
__global__ __launch_bounds__(256) void gemm128(Comp comp, const u16* __restrict__ Wt,
        const float* __restrict__ bias, void* __restrict__ outp, double* __restrict__ statsP,
        int wtStride, long outStride){
    __shared__ __align__(16) u16 As[128*72];
    __shared__ __align__(16) u16 Bs[128*72];
    __shared__ float cs2[2][128], cq2[2][128];
    const u16* W = Wt + (size_t)blockIdx.y*wtStride;
    u16*   o16 = (u16*)outp   + (size_t)blockIdx.y*outStride;
    float* o32 = (float*)outp + (size_t)blockIdx.y*outStride;
    int tid=threadIdx.x;
    int R0=blockIdx.x*128;
    int lane=tid&63, wave=tid>>6, quad=lane>>4, r16=lane&15;
    int wm=wave>>1, wn=wave&1;
    floatx4 acc[4][4]={};
#pragma unroll
    for (int ks=0;ks<2;ks++){
        int k0=ks*64;
        comp.stage(As,R0,k0,tid);
#pragma unroll
        for (int u=0;u<4;u++){
            int flat=u*256+tid, n=flat>>3, c8=flat&7;
            *(int4*)(Bs+n*72+c8*8) = *(const int4*)(W+n*HD+k0+c8*8);
        }
        __syncthreads();
#pragma unroll
        for (int kk2=0;kk2<2;kk2++){
            half8 aF[4], bF[4];
#pragma unroll
            for (int mi=0;mi<4;mi++) aF[mi]=*(const half8*)(As+(wm*64+mi*16+r16)*72 + kk2*32+quad*8);
#pragma unroll
            for (int ni=0;ni<4;ni++) bF[ni]=*(const half8*)(Bs+(wn*64+ni*16+r16)*72 + kk2*32+quad*8);
#pragma unroll
            for (int mi=0;mi<4;mi++)
#pragma unroll
                for (int ni=0;ni<4;ni++)
                    acc[mi][ni]=__builtin_amdgcn_mfma_f32_16x16x32_f16(aF[mi],bF[ni],acc[mi][ni],0,0,0);
        }
        __syncthreads();
    }
    float sAcc[4]={0,0,0,0}, qAcc[4]={0,0,0,0};
#pragma unroll
    for (int mi=0;mi<4;mi++)
#pragma unroll
        for (int ni=0;ni<4;ni++){
            int col=wn*64+ni*16+r16;
            float bv = HASBIAS ? bias[col] : 0.f;
#pragma unroll
            for (int rg=0;rg<4;rg++){
                int row=R0+wm*64+mi*16+quad*4+rg;
                float v=acc[mi][ni][rg]+bv;
                if (STATS){ sAcc[ni]+=v; qAcc[ni]+=v*v; }
                if (OUT16) o16[(size_t)row*HD+col]=f2h(v);
                else       o32[(size_t)row*HD+col]=v;
            }
        }
    if (STATS){
#pragma unroll
        for (int ni=0;ni<4;ni++){
            float s=sAcc[ni], q=qAcc[ni];
            s += __shfl_xor(s,16,64); s += __shfl_xor(s,32,64);
            q += __shfl_xor(q,16,64); q += __shfl_xor(q,32,64);
            if (quad==0){
                int col=wn*64+ni*16+r16;
                cs2[wm][col]=s; cq2[wm][col]=q;
            }
        }
        __syncthreads();
        if (tid<128){
            int slot = blockIdx.x & (NSLOT-1);
            unsafeAtomicAdd(&statsP[slot*256+tid],     (double)(cs2[0][tid]+cs2[1][tid]));
            unsafeAtomicAdd(&statsP[slot*256+128+tid], (double)(cq2[0][tid]+cq2[1][tid]));
        }
    }
}

// ---------------------------------------------------------------- softmax-aggregate + residual
// 256 threads: 4 points x 64 channel-pairs; grid NPTS/4
__global__ __launch_bounds__(256) void aggregate(const u16* __restrict__ a2, const u16* __restrict__ pose,
        const u16* __restrict__ vv, const int* __restrict__ gidx,
        const float* __restrict__ Ag2, const float* __restrict__ Cg2,
        const float* __restrict__ Ad2, const float* __restrict__ Cd2, float* __restrict__ y){
    int c=(threadIdx.x&63)*2, h=threadIdx.x>>6;
    int n=blockIdx.x*4+h;
    float sA0=Ag2[c], sC0=Cg2[c], pA0=Ad2[c], pC0=Cd2[c];
    float sA1=Ag2[c+1], sC1=Cg2[c+1], pA1=Ad2[c+1], pC1=Cd2[c+1];
    float av0[16], av1[16]; float m0=-1e30f, m1=-1e30f;
#pragma unroll
    for (int k=0;k<16;k++){
        ushort2 t=*(const ushort2*)(a2+((size_t)n*16+k)*HD+c);
        float a0=h2f(t.x)*sA0+sC0, a1=h2f(t.y)*sA1+sC1;
        av0[k]=a0; av1[k]=a1; m0=fmaxf(m0,a0); m1=fmaxf(m1,a1);
    }
    float sum0=0.f, sum1=0.f;
#pragma unroll
    for (int k=0;k<16;k++){
        float e0=__expf(av0[k]-m0), e1=__expf(av1[k]-m1);
        av0[k]=e0; av1[k]=e1; sum0+=e0; sum1+=e1;
    }
    float acc0=0.f, acc1=0.f;
#pragma unroll
    for (int k=0;k<16;k++){
        int g=gidx[n*16+k];
        ushort2 pt=*(const ushort2*)(pose+((size_t)n*16+k)*HD+c);
        ushort2 vt=*(const ushort2*)(vv+(size_t)g*HD+c);
        acc0 += av0[k]*(h2f(pt.x)*pA0+pC0 + h2f(vt.x));
        acc1 += av1[k]*(h2f(pt.y)*pA1+pC1 + h2f(vt.y));
    }
    y[(size_t)n*HD+c]  =acc0/sum0;
    y[(size_t)n*HD+c+1]=acc1/sum1;
}

__global__ __launch_bounds__(256) void residual(const float* __restrict__ ydown, const float* __restrict__ A,
        const float* __restrict__ C, const float* __restrict__ fin, float* __restrict__ fout){
    size_t i=(size_t)blockIdx.x*256+threadIdx.x; int c=(int)(i&127);
    fout[i]=ydown[i]*A[c]+C[c]+fin[i];
}

// ---------------------------------------------------------------- launch
extern "C" void kernel_launch(void* const* d_in, const int* in_sizes, int n_in,
                              void* d_out, int out_size, void* d_ws, size_t ws_size,
                              hipStream_t stream){
    const int*   coords=(const int*)d_in[0];
    const float* feats=(const float*)d_in[1];
    const float* W_top=(const float*)d_in[2];
    const float* g_top=(const float*)d_in[3];
    const float* bt_top=(const float*)d_in[4];
    const float* W_phi=(const float*)d_in[5];
    const float* W_psi=(const float*)d_in[6];
    const float* W_alp=(const float*)d_in[7];
    const float* W_d1=(const float*)d_in[8];
    const float* b_d1=(const float*)d_in[9];
    const float* g_d1=(const float*)d_in[10];
    const float* bt_d1=(const float*)d_in[11];
    const float* W_d2=(const float*)d_in[12];
    const float* b_d2=(const float*)d_in[13];
    const float* g_d2=(const float*)d_in[14];
    const float* bt_d2=(const float*)d_in[15];
    const float* W_g1=(const float*)d_in[16];
    const float* b_g1=(const float*)d_in[17];
    const float* g_g1=(const float*)d_in[18];
    const float* bt_g1=(const float*)d_in[19];
    const float* W_g2=(const float*)d_in[20];
    const float* b_g2=(const float*)d_in[21];
    const float* g_g2=(const float*)d_in[22];
    const float* bt_g2=(const float*)d_in[23];
    const float* W_dn=(const float*)d_in[24];
    const float* g_dn=(const float*)d_in[25];
    const float* bt_dn=(const float*)d_in[26];

    char* ws=(char*)d_ws;
    size_t off=0;
    auto carve=[&](size_t bytes)->char*{ char* p=ws+off; off=(off+bytes+255)&~(size_t)255; return p; };
    u32*    pc    =(u32*)   carve((size_t)NPTS*4);
    int*    idxg  =(int*)   carve((size_t)NKROWS*4);
    float*  rel   =(float*) carve((size_t)NKROWS*3*4);
    u16*    h16   =(u16*)   carve((size_t)NPTS*HD*2);
    u16*    qb    =(u16*)   carve((size_t)3*NPTS*HD*2);   // q | kpsi | v contiguous
    u16*    kpb   = qb + (size_t)NPTS*HD;
    u16*    vvb   = qb + (size_t)2*NPTS*HD;
    float*  yb    =(float*) carve((size_t)NPTS*HD*4);
    float*  ydown =(float*) carve((size_t)NPTS*HD*4);
    float*  fbuf  =(float*) carve((size_t)NPTS*HD*4);
    u16*    wt    =(u16*)   carve((size_t)8*2*16384*2);
    char*   stats =         carve(NSLOT*256*8 + 256);     // P + sM
    double* P     =(double*)stats;
    u64*    sM    =(u64*)(stats + NSLOT*256*8);
    float*  aff   =(float*) carve(8192);
    float *A_top=aff, *C_top=aff+128, *A_d2=aff+256, *C_d2=aff+384,
          *A_g1=aff+512, *C_g1=aff+640, *A_g2=aff+768, *C_g2=aff+896,
          *A_dn=aff+1024, *C_dn=aff+1152, *A_d1=aff+1280, *C_d1=aff+1536;
    u16*    pose2 =(u16*)   carve((size_t)NKROWS*HD*2);
    u16*    abuf  =(u16*)   carve((size_t)NKROWS*HD*2);
    if (ws_size < off) return;

    hipMemsetAsync(stats, 0, NSLOT*256*8 + 256, stream);
    pack_coords<<<dim3(NPTS/256),dim3(256),0,stream>>>(coords, pc);
    WPtrs wp{{W_top,W_phi,W_psi,W_alp,W_d2,W_g1,W_g2,W_dn}};
    prep_weights<<<dim3(8*2*16384/256),dim3(256),0,stream>>>(wp, wt);
    knn3<<<dim3(2048),dim3(512),0,stream>>>(pc, idxg, rel, sM);
    finalize_d1<<<dim3(1),dim3(256),0,stream>>>(sM, W_d1, b_d1, g_d1, bt_d1, A_d1, C_d1);

    const float* fin=feats;
    for (int l=0;l<2;l++){
        const u16* wt_top=wt+(0*2+l)*16384; const u16* wt_phi=wt+(1*2+l)*16384;
        const u16* wt_d2 =wt+(4*2+l)*16384; const u16* wt_g1 =wt+(5*2+l)*16384;
        const u16* wt_g2 =wt+(6*2+l)*16384; const u16* wt_dn =wt+(7*2+l)*16384;

        // h16 = f @ W_top (f16 out, stats fused)
        gemm128<CompF32,true,false,true><<<dim3(NPTS/128),dim3(256),0,stream>>>(
            CompF32{fin}, wt_top, nullptr, h16, P, 0, 0);
        finalize_affine<<<dim3(1),dim3(128),0,stream>>>(P, g_top+l*128, bt_top+l*128, (double)NPTS, A_top, C_top);

        // q / kpsi / vv in ONE launch: grid.y=3 selects weight (+2*16384) and output (+NPTS*HD)
        gemm128<CompH16Aff,true,false,false><<<dim3(NPTS/128,3),dim3(256),0,stream>>>(
            CompH16Aff{h16,A_top,C_top}, wt_phi, nullptr, qb, nullptr, 2*16384, (long)NPTS*HD);

        // pose2 = relu(BN1(rel@W_d1+b_d1)) @ W_d2 + b_d2 (stats fused)
        gemm128<CompPose1,true,true,true><<<dim3(NKROWS/128),dim3(256),0,stream>>>(
            CompPose1{rel, W_d1+l*384, b_d1+l*128, A_d1+l*128, C_d1+l*128}, wt_d2, b_d2+l*128, pose2, P, 0, 0);
        finalize_affine<<<dim3(1),dim3(128),0,stream>>>(P, g_d2+l*128, bt_d2+l*128, (double)NKROWS, A_d2, C_d2);

        // a1 = (q - kpsi[g] + BN(pose2)) @ W_g1 + b_g1 (stats fused)
        gemm128<CompA0,true,true,true><<<dim3(NKROWS/128),dim3(256),0,stream>>>(
            CompA0{qb,kpb,pose2,idxg,A_d2,C_d2}, wt_g1, b_g1+l*128, abuf, P, 0, 0);
        finalize_affine<<<dim3(1),dim3(128),0,stream>>>(P, g_g1+l*128, bt_g1+l*128, (double)NKROWS, A_g1, C_g1);

        // a2 = relu(BN(a1)) @ W_g2 + b_g2 (in-place, stats fused)
        gemm128<CompH16AffRelu,true,true,true><<<dim3(NKROWS/128),dim3(256),0,stream>>>(
            CompH16AffRelu{abuf,A_g1,C_g1}, wt_g2, b_g2+l*128, abuf, P, 0, 0);
        finalize_affine<<<dim3(1),dim3(128),0,stream>>>(P, g_g2+l*128, bt_g2+l*128, (double)NKROWS, A_g2, C_g2);

        // softmax over K + aggregate
        aggregate<<<dim3(NPTS/4),dim3(256),0,stream>>>(abuf, pose2, vvb, idxg, A_g2, C_g2, A_d2, C_d2, yb);

        // y @ W_down (stats fused) ; BN ; residual
        gemm128<CompF32,false,false,true><<<dim3(NPTS/128),dim3(256),0,stream>>>(
            CompF32{yb}, wt_dn, nullptr, ydown, P, 0, 0);
        finalize_affine<<<dim3(1),dim3(128),0,stream>>>(P, g_dn+l*128, bt_dn+l*128, (double)NPTS, A_dn, C_dn);
        residual<<<dim3(NPTS*HD/256),dim3(256),0,stream>>>(ydown, A_dn, C_dn, fin, (l==1)?(float*)d_out:fbuf);
        fin=fbuf;
    }
}